// Round 18
// baseline (220.313 us; speedup 1.0000x reference)
//
#include <hip/hip_runtime.h>
#include <hip/hip_bf16.h>
#include <stdint.h>

#define B_ 2
#define T_ 2048
#define D_ 2048
#define NH_ 16
#define NKV_ 4
#define HD_ 128
#define EQ_ (NH_*HD_)    // 2048
#define EKV_ (NKV_*HD_)  // 512
#define EQKV_ (EQ_ + 2*EKV_)   // 3072 fused row stride
#define KOFF_ EQ_              // col offset of K in fused qkv
#define VOFF_ (EQ_ + EKV_)     // col offset of V in fused qkv

typedef __attribute__((ext_vector_type(8))) short short8;
typedef __attribute__((ext_vector_type(4))) short short4x;
typedef __attribute__((ext_vector_type(4))) float floatx4;
typedef __attribute__((ext_vector_type(4))) uint uintx4;

static __device__ __forceinline__ ushort f2bf(float f) {
  uint u = __builtin_bit_cast(uint, f);
  u = (u + 0x7fffu + ((u >> 16) & 1u)) >> 16;
  return (ushort)u;
}
static __device__ __forceinline__ float bf2f(ushort u) {
  return __builtin_bit_cast(float, ((uint)u) << 16);
}
static __device__ __forceinline__ uint cvt_pk_bf16(float lo, float hi) {
  uint r;
  asm("v_cvt_pk_bf16_f32 %0, %1, %2" : "=v"(r) : "v"(lo), "v"(hi));
  return r;
}

// ---- fused prep: RMSNorm (blocks [0,NR)) + weight fp32->bf16 (rest) ------
#define S1_ (EQ_*D_)
#define S2_ (S1_ + EKV_*D_)
#define S3_ (S2_ + EKV_*D_)
#define S4_ (S3_ + D_*EQ_)
#define NR_ (B_*T_)   // rmsnorm rows
__global__ __launch_bounds__(256) void prep_k(const float* __restrict__ x,
                                              const float* __restrict__ wn,
                                              ushort* __restrict__ hb,
                                              const float* __restrict__ wq,
                                              const float* __restrict__ wk,
                                              const float* __restrict__ wv,
                                              const float* __restrict__ wo,
                                              ushort* __restrict__ wqkv,
                                              ushort* __restrict__ wob) {
  const int bx = blockIdx.x, tid = threadIdx.x;
  if (bx < NR_) {
    // ---- RMSNorm row ----
    const int w = tid >> 6, lane = tid & 63;
    const float* xr = x + (size_t)bx * D_;
    float v[8];
    float4 a = *(const float4*)&xr[tid * 8];
    float4 b = *(const float4*)&xr[tid * 8 + 4];
    v[0] = a.x; v[1] = a.y; v[2] = a.z; v[3] = a.w;
    v[4] = b.x; v[5] = b.y; v[6] = b.z; v[7] = b.w;
    float ss = 0.f;
#pragma unroll
    for (int i = 0; i < 8; i++) ss += v[i] * v[i];
    for (int m = 32; m; m >>= 1) ss += __shfl_xor(ss, m);
    __shared__ float red[4];
    if (lane == 0) red[w] = ss;
    __syncthreads();
    float tot = red[0] + red[1] + red[2] + red[3];
    float sc = rsqrtf(tot * (1.f / D_) + 1e-6f);
    short8 st;
#pragma unroll
    for (int i = 0; i < 8; i++) st[i] = (short)f2bf(v[i] * sc * wn[tid * 8 + i]);
    *(short8*)(hb + (size_t)bx * D_ + tid * 8) = st;
  } else {
    // ---- weight convert (wq|wk|wv stacked + wo) ----
    int i = ((bx - NR_) * 256 + tid) * 2;
    const float* s;
    ushort* d;
    int j;
    if (i < S1_)      { s = wq; d = wqkv + i; j = i; }
    else if (i < S2_) { s = wk; d = wqkv + i; j = i - S1_; }
    else if (i < S3_) { s = wv; d = wqkv + i; j = i - S2_; }
    else              { s = wo; d = wob + (i - S3_); j = i - S3_; }
    float2 f = *(const float2*)&s[j];
    ushort2 u;
    u.x = f2bf(f.x);
    u.y = f2bf(f.y);
    *(ushort2*)d = u;
  }
}

// ------- GEMM: C[M][N] = A[M][K] * W[N][K]^T (bf16, BK=64, dbuf-prefetch) --
// T3-minimum schedule (proven in attn_k): issue next K-tile's global_load_lds
// BEFORE computing current tile; ONE barrier per K-step (drains prefetch +
// fences buffer reuse). LDS 64KB -> 2 blocks/CU (same as VGPR-limited before).
template <bool OUT_F32>
__global__ __launch_bounds__(256) void gemm_bt(const ushort* __restrict__ A,
                                               const ushort* __restrict__ W,
                                               void* __restrict__ Cp,
                                               int M, int N, int K) {
  __shared__ __align__(16) ushort lA[2][128 * 64];
  __shared__ __align__(16) ushort lB[2][128 * 64];
  const int tid = threadIdx.x;
  const int w = tid >> 6, lane = tid & 63;
  const int bm = blockIdx.y, bn = blockIdx.x;
  const int wm = w >> 1, wn = w & 1;
  const int l15 = lane & 15, l4 = lane >> 4;
  const int swz = (l15 & 7) * 8;   // read-side XOR (row&7 == l15&7 here)

  auto stage = [&](int buf, int k0) {
#pragma unroll
    for (int r = 0; r < 4; ++r) {
      int c = r * 256 + tid;            // 16B-chunk id 0..1023
      int row = c >> 3, cw = c & 7;     // row, chunk-within-row (8/row)
      int scol = k0 + ((cw ^ (row & 7)) << 3);
      const ushort* ga = A + (size_t)(bm * 128 + row) * K + scol;
      __builtin_amdgcn_global_load_lds(
          (const __attribute__((address_space(1))) void*)ga,
          (__attribute__((address_space(3))) void*)&lA[buf][c * 8], 16, 0, 0);
      const ushort* gb = W + (size_t)(bn * 128 + row) * K + scol;
      __builtin_amdgcn_global_load_lds(
          (const __attribute__((address_space(1))) void*)gb,
          (__attribute__((address_space(3))) void*)&lB[buf][c * 8], 16, 0, 0);
    }
  };

  floatx4 acc[4][4];
#pragma unroll
  for (int m = 0; m < 4; m++)
#pragma unroll
    for (int n = 0; n < 4; n++) acc[m][n] = floatx4{0.f, 0.f, 0.f, 0.f};

  stage(0, 0);
  __syncthreads();
  int cur = 0;

  for (int k0 = 0; k0 < K; k0 += 64) {
    if (k0 + 64 < K) stage(cur ^ 1, k0 + 64);   // prefetch next K-tile
#pragma unroll
    for (int kk = 0; kk < 2; kk++) {
      short8 av[4], bv[4];
      int co = (kk * 32 + l4 * 8) ^ swz;
#pragma unroll
      for (int m = 0; m < 4; m++)
        av[m] = *(const short8*)&lA[cur][(wm * 64 + m * 16 + l15) * 64 + co];
#pragma unroll
      for (int n = 0; n < 4; n++)
        bv[n] = *(const short8*)&lB[cur][(wn * 64 + n * 16 + l15) * 64 + co];
#pragma unroll
      for (int m = 0; m < 4; m++)
#pragma unroll
        for (int n = 0; n < 4; n++)
          acc[m][n] = __builtin_amdgcn_mfma_f32_16x16x32_bf16(av[m], bv[n], acc[m][n], 0, 0, 0);
    }
    __syncthreads();   // drains prefetch; all reads of [cur] done; reuse safe
    cur ^= 1;
  }

  if (OUT_F32) {
    float* C = (float*)Cp;
#pragma unroll
    for (int m = 0; m < 4; m++)
#pragma unroll
      for (int n = 0; n < 4; n++)
#pragma unroll
        for (int j = 0; j < 4; j++) {
          int row = bm * 128 + wm * 64 + m * 16 + l4 * 4 + j;
          int col = bn * 128 + wn * 64 + n * 16 + l15;
          C[(size_t)row * N + col] = acc[m][n][j];
        }
  } else {
    ushort* C = (ushort*)Cp;
#pragma unroll
    for (int m = 0; m < 4; m++)
#pragma unroll
      for (int n = 0; n < 4; n++)
#pragma unroll
        for (int j = 0; j < 4; j++) {
          int row = bm * 128 + wm * 64 + m * 16 + l4 * 4 + j;
          int col = bn * 128 + wn * 64 + n * 16 + l15;
          C[(size_t)row * N + col] = f2bf(acc[m][n][j]);
        }
  }
}

// ---- fused post-QKV: partial RoPE (blocks [0,nrope)) + V transpose -------
__global__ __launch_bounds__(256) void pv_k(ushort* __restrict__ X,
                                            const float* __restrict__ cosT,
                                            const float* __restrict__ sinT,
                                            int rd, int nrope,
                                            ushort* __restrict__ Vt) {
  const int bx = blockIdx.x, tid = threadIdx.x;
  if (bx < nrope) {
    // ---- rope ----
    int idx = bx * 256 + tid;
    int half = rd >> 1;
    int total = B_ * T_ * (NH_ + NKV_) * half;
    if (idx >= total) return;
    int i = idx % half;
    int r2 = idx / half;
    int hh = r2 % (NH_ + NKV_);
    int row = r2 / (NH_ + NKV_);
    int t = row % T_;
    int col = (hh < NH_) ? hh * HD_ : KOFF_ + (hh - NH_) * HD_;
    ushort* p = X + (size_t)row * EQKV_ + col;
    float x0 = bf2f(p[i]), x1 = bf2f(p[i + half]);
    float c0 = cosT[t * rd + i], s0 = sinT[t * rd + i];
    float c1 = cosT[t * rd + i + half], s1 = sinT[t * rd + i + half];
    p[i] = f2bf(x0 * c0 - x1 * s0);
    p[i + half] = f2bf(x1 * c1 + x0 * s1);
  } else {
    // ---- V transpose (tile 32x32) ----
    __shared__ ushort tile[32][34];
    int j = bx - nrope;                 // 0..2047
    const int tb = j & 63, eb = (j >> 6) & 15, b = j >> 10;
    const int r = tid >> 3, c4 = (tid & 7) * 4;
    short4x in = *(const short4x*)&X[((size_t)(b * T_ + tb * 32 + r)) * EQKV_ + VOFF_ + eb * 32 + c4];
#pragma unroll
    for (int i = 0; i < 4; i++) tile[r][c4 + i] = (ushort)in[i];
    __syncthreads();
    short4x out;
#pragma unroll
    for (int i = 0; i < 4; i++) out[i] = (short)tile[c4 + i][r];
    *(short4x*)&Vt[((size_t)(b * EKV_ + eb * 32 + r)) * T_ + tb * 32 + c4] = out;
  }
}

// -------- flash attention: swapped-QK in-register softmax, fused XSA -------
// R10/R13 structure (proven 92us): paired causal q-tiles, K/V double-buffered,
// 1 barrier/tile, in-register softmax (lane owns q-row l15), shfl P-repack.
__global__ __launch_bounds__(256, 2) void attn_k(const ushort* __restrict__ QKV,
                                                 const ushort* __restrict__ Vt,
                                                 const int* __restrict__ flag,
                                                 ushort* __restrict__ att) {
  __shared__ __align__(16) ushort Klds[2][8192];
  __shared__ __align__(16) ushort Vlds[2][8192];
  const int tid = threadIdx.x, w = tid >> 6, lane = tid & 63;
  const int l15 = lane & 15, l4 = lane >> 4;
  const int alpha = lane >> 5;                    // target alpha for P repack
  const int srcA = ((lane >> 4) & 1) * 32 + l15;  // P repack source lanes
  const int srcB = srcA + 16;
  const int h = blockIdx.y, b = blockIdx.z, kv = h >> 2;
  const int px = blockIdx.x;
  const float c_ = 0.12752626f;   // (1/sqrt(128)) * log2(e)
  const float THR_ = 90.5f;       // 8 / scale (raw-score units)
  const int flagv = *flag;

  const ushort* Kh = QKV + KOFF_ + (size_t)b * T_ * EQKV_ + kv * HD_;  // + t*EQKV_
  const ushort* Vth = Vt + ((size_t)(b * EKV_ + kv * HD_)) * T_;       // + d*T_

  auto stageK = [&](int buf, const ushort* kp) {
#pragma unroll
    for (int i = 0; i < 4; i++) {
      int q = i * 256 + tid;          // 16B-chunk id, 0..1023
      int r = q >> 4, cw = q & 15;    // row, chunk-within-row (16 chunks)
      const ushort* src = kp + (size_t)r * EQKV_ + ((cw ^ (r & 7)) << 3);
      __builtin_amdgcn_global_load_lds(
          (const __attribute__((address_space(1))) void*)src,
          (__attribute__((address_space(3))) void*)&Klds[buf][q * 8], 16, 0, 0);
    }
  };
  auto stageV = [&](int buf, const ushort* vp) {
#pragma unroll
    for (int i = 0; i < 4; i++) {
      int q = i * 256 + tid;          // 16B-chunk id, 0..1023
      int d = q >> 3, cw = q & 7;     // d-row, chunk-within-row (8 chunks)
      const ushort* src = vp + (size_t)d * T_ + ((cw ^ (d & 7)) << 3);
      __builtin_amdgcn_global_load_lds(
          (const __attribute__((address_space(1))) void*)src,
          (__attribute__((address_space(3))) void*)&Vlds[buf][q * 8], 16, 0, 0);
    }
  };

  for (int hh = 0; hh < 2; hh++) {
    const int qb = hh ? (31 - px) : px;   // causal pairing: px + (31-px) = 33 tiles
    const int nt = qb + 1;
    const int qbase = qb * 64 + w * 16;
    const int myq = qbase + l15;          // this lane's q-row (softmax side)

    short8 qf[4];
#pragma unroll
    for (int kk = 0; kk < 4; kk++)
      qf[kk] = *(const short8*)&QKV[(size_t)(b * T_ + qbase + l15) * EQKV_ + h * HD_ + kk * 32 + l4 * 8];

    floatx4 acc_o[8];
#pragma unroll
    for (int nn = 0; nn < 8; nn++) acc_o[nn] = floatx4{0.f, 0.f, 0.f, 0.f};
    float m_ = -1e30f;
    float l_ = 0.f;

    const ushort* kp = Kh;   // advances 64*EQKV_ per tile
    const ushort* vp = Vth;  // advances 64 per tile
    stageV(0, vp);
    stageK(0, kp);
    __syncthreads();
    int cur = 0;

    for (int t = 0; t < nt; t++) {
      if (t + 1 < nt) {                 // prefetch next tile; lands by end barrier
        stageV(cur ^ 1, vp + 64);
        stageK(cur ^ 1, kp + 64 * EQKV_);
      }
      kp += 64 * EQKV_;
      vp += 64;

      // ---- QK^T swapped: s = K x Q -> S^T; lane: q=l15, k=n*16+l4*4+j ----
      floatx4 s[4];
#pragma unroll
      for (int n = 0; n < 4; n++) s[n] = floatx4{0.f, 0.f, 0.f, 0.f};
      __builtin_amdgcn_s_setprio(1);
#pragma unroll
      for (int n = 0; n < 4; n++) {
        int row = n * 16 + l15;
#pragma unroll
        for (int kk = 0; kk < 4; kk++) {
          int bc = (kk * 64 + l4 * 16) ^ ((row & 7) << 4);
          short8 kf = *(const short8*)&Klds[cur][row * 128 + (bc >> 1)];
          s[n] = __builtin_amdgcn_mfma_f32_16x16x32_bf16(kf, qf[kk], s[n], 0, 0, 0);
        }
      }
      __builtin_amdgcn_s_setprio(0);

      // ---- causal mask (diagonal tile only) + per-lane row max ----
      float pm = -1e30f;
      if (t == nt - 1) {
#pragma unroll
        for (int n = 0; n < 4; n++)
#pragma unroll
          for (int j = 0; j < 4; j++) {
            int k = t * 64 + n * 16 + l4 * 4 + j;
            float sv = (k <= myq) ? s[n][j] : -1e30f;
            s[n][j] = sv;
            pm = fmaxf(pm, sv);
          }
      } else {
#pragma unroll
        for (int n = 0; n < 4; n++)
#pragma unroll
          for (int j = 0; j < 4; j++) pm = fmaxf(pm, s[n][j]);
      }
      pm = fmaxf(pm, __shfl_xor(pm, 16));
      pm = fmaxf(pm, __shfl_xor(pm, 32));

      if (!__all(pm - m_ <= THR_)) {    // defer-max: skip rescale if growth small
        float mn = fmaxf(m_, pm);
        float f = exp2f((m_ - mn) * c_);
        m_ = mn;
        l_ *= f;
        float fj0 = __shfl(f, l4 * 4 + 0);
        float fj1 = __shfl(f, l4 * 4 + 1);
        float fj2 = __shfl(f, l4 * 4 + 2);
        float fj3 = __shfl(f, l4 * 4 + 3);
#pragma unroll
        for (int nn = 0; nn < 8; nn++) {
          acc_o[nn][0] *= fj0;
          acc_o[nn][1] *= fj1;
          acc_o[nn][2] *= fj2;
          acc_o[nn][3] *= fj3;
        }
      }

      // ---- exp in-register + pack to bf16 pairs ----
      float mc = m_ * c_;
      float ps = 0.f;
      float p_[4][4];
#pragma unroll
      for (int n = 0; n < 4; n++)
#pragma unroll
        for (int j = 0; j < 4; j++) {
          float p = exp2f(__builtin_fmaf(s[n][j], c_, -mc));
          p_[n][j] = p;
          ps += p;
        }
      ps += __shfl_xor(ps, 16);
      ps += __shfl_xor(ps, 32);
      l_ += ps;
      uint pk01[4], pk23[4];
#pragma unroll
      for (int n = 0; n < 4; n++) {
        pk01[n] = cvt_pk_bf16(p_[n][0], p_[n][1]);
        pk23[n] = cvt_pk_bf16(p_[n][2], p_[n][3]);
      }

      // ---- PV: build P A-fragments via shfl, V from Vlds[cur] ----
      __builtin_amdgcn_s_setprio(1);
#pragma unroll
      for (int kk = 0; kk < 2; kk++) {
        int a01_0 = __shfl((int)pk01[2 * kk + 0], srcA);
        int a01_1 = __shfl((int)pk01[2 * kk + 1], srcA);
        int a23_0 = __shfl((int)pk23[2 * kk + 0], srcA);
        int a23_1 = __shfl((int)pk23[2 * kk + 1], srcA);
        int b01_0 = __shfl((int)pk01[2 * kk + 0], srcB);
        int b01_1 = __shfl((int)pk01[2 * kk + 1], srcB);
        int b23_0 = __shfl((int)pk23[2 * kk + 0], srcB);
        int b23_1 = __shfl((int)pk23[2 * kk + 1], srcB);
        uintx4 du;
        du.x = (uint)(alpha ? a01_1 : a01_0);
        du.y = (uint)(alpha ? a23_1 : a23_0);
        du.z = (uint)(alpha ? b01_1 : b01_0);
        du.w = (uint)(alpha ? b23_1 : b23_0);
        short8 pa = __builtin_bit_cast(short8, du);
#pragma unroll
        for (int n = 0; n < 8; n++) {
          int d = n * 16 + l15;
          int bc = (kk * 64 + l4 * 16) ^ ((d & 7) << 4);
          short8 vf = *(const short8*)&Vlds[cur][d * 64 + (bc >> 1)];
          acc_o[n] = __builtin_amdgcn_mfma_f32_16x16x32_bf16(pa, vf, acc_o[n], 0, 0, 0);
        }
      }
      __builtin_amdgcn_s_setprio(0);
      __syncthreads();   // drains prefetch; all reads of [cur] done; restage safe
      cur ^= 1;
    }

    // ---- epilogue: normalize + fused XSA + bf16 store to att[b][t][e] ----
    float inv_ = 1.f / l_;
#pragma unroll
    for (int j = 0; j < 4; j++) {
      float inv = __shfl(inv_, l4 * 4 + j);
      int q = qbase + l4 * 4 + j;
      const ushort* vq = QKV + VOFF_ + (size_t)(b * T_ + q) * EQKV_ + kv * HD_;
      float ov[8], vv[8], dot = 0.f, vns = 0.f;
#pragma unroll
      for (int n = 0; n < 8; n++) {
        float o = acc_o[n][j] * inv;
        float v = bf2f(vq[n * 16 + l15]);
        ov[n] = o;
        vv[n] = v;
        dot += o * v;
        vns += v * v;
      }
      dot += __shfl_xor(dot, 1); vns += __shfl_xor(vns, 1);
      dot += __shfl_xor(dot, 2); vns += __shfl_xor(vns, 2);
      dot += __shfl_xor(dot, 4); vns += __shfl_xor(vns, 4);
      dot += __shfl_xor(dot, 8); vns += __shfl_xor(vns, 8);
      if (flagv) {
        float f = dot / (vns + 1e-6f);
#pragma unroll
        for (int n = 0; n < 8; n++) ov[n] -= f * vv[n];
      }
      ushort* ap = att + (size_t)(b * T_ + q) * EQ_ + h * HD_;
#pragma unroll
      for (int n = 0; n < 8; n++) ap[n * 16 + l15] = f2bf(ov[n]);
    }
  }
}

extern "C" void kernel_launch(void* const* d_in, const int* in_sizes, int n_in,
                              void* d_out, int out_size, void* d_ws, size_t ws_size,
                              hipStream_t stream) {
  const float* x    = (const float*)d_in[0];
  const float* cosT = (const float*)d_in[1];
  const float* sinT = (const float*)d_in[2];
  const float* wn   = (const float*)d_in[3];
  const float* wq   = (const float*)d_in[4];
  const float* wk   = (const float*)d_in[5];
  const float* wv   = (const float*)d_in[6];
  const float* wo   = (const float*)d_in[7];
  const int* use_xsa = (const int*)d_in[9];
  int rd = in_sizes[1] / T_;  // cos table is (T, rd)

  char* ws = (char*)d_ws;
  size_t off = 0;
  auto alloc = [&](size_t bytes) {
    char* p = ws + off;
    off += (bytes + 255) & ~(size_t)255;
    return p;
  };
  ushort* h_b    = (ushort*)alloc((size_t)B_ * T_ * D_ * 2);
  ushort* qkv_b  = (ushort*)alloc((size_t)B_ * T_ * EQKV_ * 2);
  ushort* wqkv_b = (ushort*)alloc((size_t)EQKV_ * D_ * 2);
  ushort* wo_b   = (ushort*)alloc((size_t)D_ * EQ_ * 2);
  ushort* att_b  = h_b;     // reuse h region (dead after QKV GEMM)
  ushort* vt_b   = wqkv_b;  // reuse wqkv region (dead after QKV GEMM); 4MB of 12MB

  // fused prep: rmsnorm rows + weight converts in one dispatch
  prep_k<<<NR_ + S4_ / 512, 256, 0, stream>>>(x, wn, h_b, wq, wk, wv, wo,
                                              wqkv_b, wo_b);

  // fused QKV projection: [B*T][3072] = h[B*T][2048] @ wqkv^T  (768 WGs)
  dim3 gqkv(EQKV_ / 128, B_ * T_ / 128);
  gemm_bt<false><<<gqkv, 256, 0, stream>>>(h_b, wqkv_b, qkv_b, B_ * T_, EQKV_, D_);

  // fused post: Q+K RoPE + V transpose in one dispatch
  int half = rd / 2;
  int tot = B_ * T_ * (NH_ + NKV_) * half;
  int nrope = (tot + 255) / 256;
  int nvtr = (T_ / 32) * (EKV_ / 32) * B_;
  pv_k<<<nrope + nvtr, 256, 0, stream>>>(qkv_b, cosT, sinT, rd, nrope, vt_b);

  dim3 ga(16, NH_, B_);   // paired causal q-tiles: px + (31-px)
  attn_k<<<ga, 256, 0, stream>>>(qkv_b, vt_b, use_xsa, att_b);

  dim3 go(D_ / 128, B_ * T_ / 128);
  gemm_bt<true><<<go, 256, 0, stream>>>(att_b, wo_b, d_out, B_ * T_, D_, D_);
}

// Round 19
// 208.123 us; speedup vs baseline: 1.0586x; 1.0586x over previous
//
#include <hip/hip_runtime.h>
#include <hip/hip_bf16.h>
#include <stdint.h>

#define B_ 2
#define T_ 2048
#define D_ 2048
#define NH_ 16
#define NKV_ 4
#define HD_ 128
#define EQ_ (NH_*HD_)    // 2048
#define EKV_ (NKV_*HD_)  // 512
#define EQKV_ (EQ_ + 2*EKV_)   // 3072 fused row stride
#define KOFF_ EQ_              // col offset of K in fused qkv
#define VOFF_ (EQ_ + EKV_)     // col offset of V in fused qkv

typedef __attribute__((ext_vector_type(8))) short short8;
typedef __attribute__((ext_vector_type(4))) short short4x;
typedef __attribute__((ext_vector_type(4))) float floatx4;
typedef __attribute__((ext_vector_type(4))) uint uintx4;

static __device__ __forceinline__ ushort f2bf(float f) {
  uint u = __builtin_bit_cast(uint, f);
  u = (u + 0x7fffu + ((u >> 16) & 1u)) >> 16;
  return (ushort)u;
}
static __device__ __forceinline__ float bf2f(ushort u) {
  return __builtin_bit_cast(float, ((uint)u) << 16);
}
static __device__ __forceinline__ uint cvt_pk_bf16(float lo, float hi) {
  uint r;
  asm("v_cvt_pk_bf16_f32 %0, %1, %2" : "=v"(r) : "v"(lo), "v"(hi));
  return r;
}

// ---- fused prep: RMSNorm (blocks [0,NR)) + weight fp32->bf16 (rest) ------
#define S1_ (EQ_*D_)
#define S2_ (S1_ + EKV_*D_)
#define S3_ (S2_ + EKV_*D_)
#define S4_ (S3_ + D_*EQ_)
#define NR_ (B_*T_)   // rmsnorm rows
__global__ __launch_bounds__(256) void prep_k(const float* __restrict__ x,
                                              const float* __restrict__ wn,
                                              ushort* __restrict__ hb,
                                              const float* __restrict__ wq,
                                              const float* __restrict__ wk,
                                              const float* __restrict__ wv,
                                              const float* __restrict__ wo,
                                              ushort* __restrict__ wqkv,
                                              ushort* __restrict__ wob) {
  const int bx = blockIdx.x, tid = threadIdx.x;
  if (bx < NR_) {
    // ---- RMSNorm row ----
    const int w = tid >> 6, lane = tid & 63;
    const float* xr = x + (size_t)bx * D_;
    float v[8];
    float4 a = *(const float4*)&xr[tid * 8];
    float4 b = *(const float4*)&xr[tid * 8 + 4];
    v[0] = a.x; v[1] = a.y; v[2] = a.z; v[3] = a.w;
    v[4] = b.x; v[5] = b.y; v[6] = b.z; v[7] = b.w;
    float ss = 0.f;
#pragma unroll
    for (int i = 0; i < 8; i++) ss += v[i] * v[i];
    for (int m = 32; m; m >>= 1) ss += __shfl_xor(ss, m);
    __shared__ float red[4];
    if (lane == 0) red[w] = ss;
    __syncthreads();
    float tot = red[0] + red[1] + red[2] + red[3];
    float sc = rsqrtf(tot * (1.f / D_) + 1e-6f);
    short8 st;
#pragma unroll
    for (int i = 0; i < 8; i++) st[i] = (short)f2bf(v[i] * sc * wn[tid * 8 + i]);
    *(short8*)(hb + (size_t)bx * D_ + tid * 8) = st;
  } else {
    // ---- weight convert (wq|wk|wv stacked + wo) ----
    int i = ((bx - NR_) * 256 + tid) * 2;
    const float* s;
    ushort* d;
    int j;
    if (i < S1_)      { s = wq; d = wqkv + i; j = i; }
    else if (i < S2_) { s = wk; d = wqkv + i; j = i - S1_; }
    else if (i < S3_) { s = wv; d = wqkv + i; j = i - S2_; }
    else              { s = wo; d = wob + (i - S3_); j = i - S3_; }
    float2 f = *(const float2*)&s[j];
    ushort2 u;
    u.x = f2bf(f.x);
    u.y = f2bf(f.y);
    *(ushort2*)d = u;
  }
}

// ---------------- GEMM: C[M][N] = A[M][K] * W[N][K]^T (bf16, BK=64) -------
// Single-buffered 2-barrier loop: measured FASTER than explicit dbuf
// (R17 208.5us vs R18 220us) — dbuf halves blocks/CU (LDS 64KB) and loses
// the cross-block wave overlap that hides staging latency.
template <bool OUT_F32>
__global__ __launch_bounds__(256) void gemm_bt(const ushort* __restrict__ A,
                                               const ushort* __restrict__ W,
                                               void* __restrict__ Cp,
                                               int M, int N, int K) {
  __shared__ __align__(16) ushort lA[128 * 64];
  __shared__ __align__(16) ushort lB[128 * 64];
  const int tid = threadIdx.x;
  const int w = tid >> 6, lane = tid & 63;
  const int bm = blockIdx.y, bn = blockIdx.x;
  const int wm = w >> 1, wn = w & 1;
  const int l15 = lane & 15, l4 = lane >> 4;
  const int swz = (l15 & 7) * 8;   // read-side XOR (row&7 == l15&7 here)

  floatx4 acc[4][4];
#pragma unroll
  for (int m = 0; m < 4; m++)
#pragma unroll
    for (int n = 0; n < 4; n++) acc[m][n] = floatx4{0.f, 0.f, 0.f, 0.f};

  for (int k0 = 0; k0 < K; k0 += 64) {
#pragma unroll
    for (int r = 0; r < 4; ++r) {
      int c = r * 256 + tid;            // 16B-chunk id 0..1023
      int row = c >> 3, cw = c & 7;     // row, chunk-within-row (8/row)
      int scol = k0 + ((cw ^ (row & 7)) << 3);
      const ushort* ga = A + (size_t)(bm * 128 + row) * K + scol;
      __builtin_amdgcn_global_load_lds(
          (const __attribute__((address_space(1))) void*)ga,
          (__attribute__((address_space(3))) void*)&lA[c * 8], 16, 0, 0);
      const ushort* gb = W + (size_t)(bn * 128 + row) * K + scol;
      __builtin_amdgcn_global_load_lds(
          (const __attribute__((address_space(1))) void*)gb,
          (__attribute__((address_space(3))) void*)&lB[c * 8], 16, 0, 0);
    }
    __syncthreads();
#pragma unroll
    for (int kk = 0; kk < 2; kk++) {
      short8 av[4], bv[4];
      int co = (kk * 32 + l4 * 8) ^ swz;
#pragma unroll
      for (int m = 0; m < 4; m++)
        av[m] = *(const short8*)&lA[(wm * 64 + m * 16 + l15) * 64 + co];
#pragma unroll
      for (int n = 0; n < 4; n++)
        bv[n] = *(const short8*)&lB[(wn * 64 + n * 16 + l15) * 64 + co];
#pragma unroll
      for (int m = 0; m < 4; m++)
#pragma unroll
        for (int n = 0; n < 4; n++)
          acc[m][n] = __builtin_amdgcn_mfma_f32_16x16x32_bf16(av[m], bv[n], acc[m][n], 0, 0, 0);
    }
    __syncthreads();
  }

  if (OUT_F32) {
    float* C = (float*)Cp;
#pragma unroll
    for (int m = 0; m < 4; m++)
#pragma unroll
      for (int n = 0; n < 4; n++)
#pragma unroll
        for (int j = 0; j < 4; j++) {
          int row = bm * 128 + wm * 64 + m * 16 + l4 * 4 + j;
          int col = bn * 128 + wn * 64 + n * 16 + l15;
          C[(size_t)row * N + col] = acc[m][n][j];
        }
  } else {
    ushort* C = (ushort*)Cp;
#pragma unroll
    for (int m = 0; m < 4; m++)
#pragma unroll
      for (int n = 0; n < 4; n++)
#pragma unroll
        for (int j = 0; j < 4; j++) {
          int row = bm * 128 + wm * 64 + m * 16 + l4 * 4 + j;
          int col = bn * 128 + wn * 64 + n * 16 + l15;
          C[(size_t)row * N + col] = f2bf(acc[m][n][j]);
        }
  }
}

// ---- fused post-QKV: partial RoPE (blocks [0,nrope)) + V transpose -------
__global__ __launch_bounds__(256) void pv_k(ushort* __restrict__ X,
                                            const float* __restrict__ cosT,
                                            const float* __restrict__ sinT,
                                            int rd, int nrope,
                                            ushort* __restrict__ Vt) {
  const int bx = blockIdx.x, tid = threadIdx.x;
  if (bx < nrope) {
    // ---- rope ----
    int idx = bx * 256 + tid;
    int half = rd >> 1;
    int total = B_ * T_ * (NH_ + NKV_) * half;
    if (idx >= total) return;
    int i = idx % half;
    int r2 = idx / half;
    int hh = r2 % (NH_ + NKV_);
    int row = r2 / (NH_ + NKV_);
    int t = row % T_;
    int col = (hh < NH_) ? hh * HD_ : KOFF_ + (hh - NH_) * HD_;
    ushort* p = X + (size_t)row * EQKV_ + col;
    float x0 = bf2f(p[i]), x1 = bf2f(p[i + half]);
    float c0 = cosT[t * rd + i], s0 = sinT[t * rd + i];
    float c1 = cosT[t * rd + i + half], s1 = sinT[t * rd + i + half];
    p[i] = f2bf(x0 * c0 - x1 * s0);
    p[i + half] = f2bf(x1 * c1 + x0 * s1);
  } else {
    // ---- V transpose (tile 32x32) ----
    __shared__ ushort tile[32][34];
    int j = bx - nrope;                 // 0..2047
    const int tb = j & 63, eb = (j >> 6) & 15, b = j >> 10;
    const int r = tid >> 3, c4 = (tid & 7) * 4;
    short4x in = *(const short4x*)&X[((size_t)(b * T_ + tb * 32 + r)) * EQKV_ + VOFF_ + eb * 32 + c4];
#pragma unroll
    for (int i = 0; i < 4; i++) tile[r][c4 + i] = (ushort)in[i];
    __syncthreads();
    short4x out;
#pragma unroll
    for (int i = 0; i < 4; i++) out[i] = (short)tile[c4 + i][r];
    *(short4x*)&Vt[((size_t)(b * EKV_ + eb * 32 + r)) * T_ + tb * 32 + c4] = out;
  }
}

// -------- flash attention: swapped-QK in-register softmax, fused XSA -------
// R10/R13 structure (proven 92us): paired causal q-tiles, K/V double-buffered,
// 1 barrier/tile, in-register softmax (lane owns q-row l15), shfl P-repack.
__global__ __launch_bounds__(256, 2) void attn_k(const ushort* __restrict__ QKV,
                                                 const ushort* __restrict__ Vt,
                                                 const int* __restrict__ flag,
                                                 ushort* __restrict__ att) {
  __shared__ __align__(16) ushort Klds[2][8192];
  __shared__ __align__(16) ushort Vlds[2][8192];
  const int tid = threadIdx.x, w = tid >> 6, lane = tid & 63;
  const int l15 = lane & 15, l4 = lane >> 4;
  const int alpha = lane >> 5;                    // target alpha for P repack
  const int srcA = ((lane >> 4) & 1) * 32 + l15;  // P repack source lanes
  const int srcB = srcA + 16;
  const int h = blockIdx.y, b = blockIdx.z, kv = h >> 2;
  const int px = blockIdx.x;
  const float c_ = 0.12752626f;   // (1/sqrt(128)) * log2(e)
  const float THR_ = 90.5f;       // 8 / scale (raw-score units)
  const int flagv = *flag;

  const ushort* Kh = QKV + KOFF_ + (size_t)b * T_ * EQKV_ + kv * HD_;  // + t*EQKV_
  const ushort* Vth = Vt + ((size_t)(b * EKV_ + kv * HD_)) * T_;       // + d*T_

  auto stageK = [&](int buf, const ushort* kp) {
#pragma unroll
    for (int i = 0; i < 4; i++) {
      int q = i * 256 + tid;          // 16B-chunk id, 0..1023
      int r = q >> 4, cw = q & 15;    // row, chunk-within-row (16 chunks)
      const ushort* src = kp + (size_t)r * EQKV_ + ((cw ^ (r & 7)) << 3);
      __builtin_amdgcn_global_load_lds(
          (const __attribute__((address_space(1))) void*)src,
          (__attribute__((address_space(3))) void*)&Klds[buf][q * 8], 16, 0, 0);
    }
  };
  auto stageV = [&](int buf, const ushort* vp) {
#pragma unroll
    for (int i = 0; i < 4; i++) {
      int q = i * 256 + tid;          // 16B-chunk id, 0..1023
      int d = q >> 3, cw = q & 7;     // d-row, chunk-within-row (8 chunks)
      const ushort* src = vp + (size_t)d * T_ + ((cw ^ (d & 7)) << 3);
      __builtin_amdgcn_global_load_lds(
          (const __attribute__((address_space(1))) void*)src,
          (__attribute__((address_space(3))) void*)&Vlds[buf][q * 8], 16, 0, 0);
    }
  };

  for (int hh = 0; hh < 2; hh++) {
    const int qb = hh ? (31 - px) : px;   // causal pairing: px + (31-px) = 33 tiles
    const int nt = qb + 1;
    const int qbase = qb * 64 + w * 16;
    const int myq = qbase + l15;          // this lane's q-row (softmax side)

    short8 qf[4];
#pragma unroll
    for (int kk = 0; kk < 4; kk++)
      qf[kk] = *(const short8*)&QKV[(size_t)(b * T_ + qbase + l15) * EQKV_ + h * HD_ + kk * 32 + l4 * 8];

    floatx4 acc_o[8];
#pragma unroll
    for (int nn = 0; nn < 8; nn++) acc_o[nn] = floatx4{0.f, 0.f, 0.f, 0.f};
    float m_ = -1e30f;
    float l_ = 0.f;

    const ushort* kp = Kh;   // advances 64*EQKV_ per tile
    const ushort* vp = Vth;  // advances 64 per tile
    stageV(0, vp);
    stageK(0, kp);
    __syncthreads();
    int cur = 0;

    for (int t = 0; t < nt; t++) {
      if (t + 1 < nt) {                 // prefetch next tile; lands by end barrier
        stageV(cur ^ 1, vp + 64);
        stageK(cur ^ 1, kp + 64 * EQKV_);
      }
      kp += 64 * EQKV_;
      vp += 64;

      // ---- QK^T swapped: s = K x Q -> S^T; lane: q=l15, k=n*16+l4*4+j ----
      floatx4 s[4];
#pragma unroll
      for (int n = 0; n < 4; n++) s[n] = floatx4{0.f, 0.f, 0.f, 0.f};
      __builtin_amdgcn_s_setprio(1);
#pragma unroll
      for (int n = 0; n < 4; n++) {
        int row = n * 16 + l15;
#pragma unroll
        for (int kk = 0; kk < 4; kk++) {
          int bc = (kk * 64 + l4 * 16) ^ ((row & 7) << 4);
          short8 kf = *(const short8*)&Klds[cur][row * 128 + (bc >> 1)];
          s[n] = __builtin_amdgcn_mfma_f32_16x16x32_bf16(kf, qf[kk], s[n], 0, 0, 0);
        }
      }
      __builtin_amdgcn_s_setprio(0);

      // ---- causal mask (diagonal tile only) + per-lane row max ----
      float pm = -1e30f;
      if (t == nt - 1) {
#pragma unroll
        for (int n = 0; n < 4; n++)
#pragma unroll
          for (int j = 0; j < 4; j++) {
            int k = t * 64 + n * 16 + l4 * 4 + j;
            float sv = (k <= myq) ? s[n][j] : -1e30f;
            s[n][j] = sv;
            pm = fmaxf(pm, sv);
          }
      } else {
#pragma unroll
        for (int n = 0; n < 4; n++)
#pragma unroll
          for (int j = 0; j < 4; j++) pm = fmaxf(pm, s[n][j]);
      }
      pm = fmaxf(pm, __shfl_xor(pm, 16));
      pm = fmaxf(pm, __shfl_xor(pm, 32));

      if (!__all(pm - m_ <= THR_)) {    // defer-max: skip rescale if growth small
        float mn = fmaxf(m_, pm);
        float f = exp2f((m_ - mn) * c_);
        m_ = mn;
        l_ *= f;
        float fj0 = __shfl(f, l4 * 4 + 0);
        float fj1 = __shfl(f, l4 * 4 + 1);
        float fj2 = __shfl(f, l4 * 4 + 2);
        float fj3 = __shfl(f, l4 * 4 + 3);
#pragma unroll
        for (int nn = 0; nn < 8; nn++) {
          acc_o[nn][0] *= fj0;
          acc_o[nn][1] *= fj1;
          acc_o[nn][2] *= fj2;
          acc_o[nn][3] *= fj3;
        }
      }

      // ---- exp in-register + pack to bf16 pairs ----
      float mc = m_ * c_;
      float ps = 0.f;
      float p_[4][4];
#pragma unroll
      for (int n = 0; n < 4; n++)
#pragma unroll
        for (int j = 0; j < 4; j++) {
          float p = exp2f(__builtin_fmaf(s[n][j], c_, -mc));
          p_[n][j] = p;
          ps += p;
        }
      ps += __shfl_xor(ps, 16);
      ps += __shfl_xor(ps, 32);
      l_ += ps;
      uint pk01[4], pk23[4];
#pragma unroll
      for (int n = 0; n < 4; n++) {
        pk01[n] = cvt_pk_bf16(p_[n][0], p_[n][1]);
        pk23[n] = cvt_pk_bf16(p_[n][2], p_[n][3]);
      }

      // ---- PV: build P A-fragments via shfl, V from Vlds[cur] ----
      __builtin_amdgcn_s_setprio(1);
#pragma unroll
      for (int kk = 0; kk < 2; kk++) {
        int a01_0 = __shfl((int)pk01[2 * kk + 0], srcA);
        int a01_1 = __shfl((int)pk01[2 * kk + 1], srcA);
        int a23_0 = __shfl((int)pk23[2 * kk + 0], srcA);
        int a23_1 = __shfl((int)pk23[2 * kk + 1], srcA);
        int b01_0 = __shfl((int)pk01[2 * kk + 0], srcB);
        int b01_1 = __shfl((int)pk01[2 * kk + 1], srcB);
        int b23_0 = __shfl((int)pk23[2 * kk + 0], srcB);
        int b23_1 = __shfl((int)pk23[2 * kk + 1], srcB);
        uintx4 du;
        du.x = (uint)(alpha ? a01_1 : a01_0);
        du.y = (uint)(alpha ? a23_1 : a23_0);
        du.z = (uint)(alpha ? b01_1 : b01_0);
        du.w = (uint)(alpha ? b23_1 : b23_0);
        short8 pa = __builtin_bit_cast(short8, du);
#pragma unroll
        for (int n = 0; n < 8; n++) {
          int d = n * 16 + l15;
          int bc = (kk * 64 + l4 * 16) ^ ((d & 7) << 4);
          short8 vf = *(const short8*)&Vlds[cur][d * 64 + (bc >> 1)];
          acc_o[n] = __builtin_amdgcn_mfma_f32_16x16x32_bf16(pa, vf, acc_o[n], 0, 0, 0);
        }
      }
      __builtin_amdgcn_s_setprio(0);
      __syncthreads();   // drains prefetch; all reads of [cur] done; restage safe
      cur ^= 1;
    }

    // ---- epilogue: normalize + fused XSA + bf16 store to att[b][t][e] ----
    float inv_ = 1.f / l_;
#pragma unroll
    for (int j = 0; j < 4; j++) {
      float inv = __shfl(inv_, l4 * 4 + j);
      int q = qbase + l4 * 4 + j;
      const ushort* vq = QKV + VOFF_ + (size_t)(b * T_ + q) * EQKV_ + kv * HD_;
      float ov[8], vv[8], dot = 0.f, vns = 0.f;
#pragma unroll
      for (int n = 0; n < 8; n++) {
        float o = acc_o[n][j] * inv;
        float v = bf2f(vq[n * 16 + l15]);
        ov[n] = o;
        vv[n] = v;
        dot += o * v;
        vns += v * v;
      }
      dot += __shfl_xor(dot, 1); vns += __shfl_xor(vns, 1);
      dot += __shfl_xor(dot, 2); vns += __shfl_xor(vns, 2);
      dot += __shfl_xor(dot, 4); vns += __shfl_xor(vns, 4);
      dot += __shfl_xor(dot, 8); vns += __shfl_xor(vns, 8);
      if (flagv) {
        float f = dot / (vns + 1e-6f);
#pragma unroll
        for (int n = 0; n < 8; n++) ov[n] -= f * vv[n];
      }
      ushort* ap = att + (size_t)(b * T_ + q) * EQ_ + h * HD_;
#pragma unroll
      for (int n = 0; n < 8; n++) ap[n * 16 + l15] = f2bf(ov[n]);
    }
  }
}

extern "C" void kernel_launch(void* const* d_in, const int* in_sizes, int n_in,
                              void* d_out, int out_size, void* d_ws, size_t ws_size,
                              hipStream_t stream) {
  const float* x    = (const float*)d_in[0];
  const float* cosT = (const float*)d_in[1];
  const float* sinT = (const float*)d_in[2];
  const float* wn   = (const float*)d_in[3];
  const float* wq   = (const float*)d_in[4];
  const float* wk   = (const float*)d_in[5];
  const float* wv   = (const float*)d_in[6];
  const float* wo   = (const float*)d_in[7];
  const int* use_xsa = (const int*)d_in[9];
  int rd = in_sizes[1] / T_;  // cos table is (T, rd)

  char* ws = (char*)d_ws;
  size_t off = 0;
  auto alloc = [&](size_t bytes) {
    char* p = ws + off;
    off += (bytes + 255) & ~(size_t)255;
    return p;
  };
  ushort* h_b    = (ushort*)alloc((size_t)B_ * T_ * D_ * 2);
  ushort* qkv_b  = (ushort*)alloc((size_t)B_ * T_ * EQKV_ * 2);
  ushort* wqkv_b = (ushort*)alloc((size_t)EQKV_ * D_ * 2);
  ushort* wo_b   = (ushort*)alloc((size_t)D_ * EQ_ * 2);
  ushort* att_b  = h_b;     // reuse h region (dead after QKV GEMM)
  ushort* vt_b   = wqkv_b;  // reuse wqkv region (dead after QKV GEMM); 4MB of 12MB

  // fused prep: rmsnorm rows + weight converts in one dispatch
  prep_k<<<NR_ + S4_ / 512, 256, 0, stream>>>(x, wn, h_b, wq, wk, wv, wo,
                                              wqkv_b, wo_b);

  // fused QKV projection: [B*T][3072] = h[B*T][2048] @ wqkv^T  (768 WGs)
  dim3 gqkv(EQKV_ / 128, B_ * T_ / 128);
  gemm_bt<false><<<gqkv, 256, 0, stream>>>(h_b, wqkv_b, qkv_b, B_ * T_, EQKV_, D_);

  // fused post: Q+K RoPE + V transpose in one dispatch
  int half = rd / 2;
  int tot = B_ * T_ * (NH_ + NKV_) * half;
  int nrope = (tot + 255) / 256;
  int nvtr = (T_ / 32) * (EKV_ / 32) * B_;
  pv_k<<<nrope + nvtr, 256, 0, stream>>>(qkv_b, cosT, sinT, rd, nrope, vt_b);

  dim3 ga(16, NH_, B_);   // paired causal q-tiles: px + (31-px)
  attn_k<<<ga, 256, 0, stream>>>(qkv_b, vt_b, use_xsa, att_b);

  dim3 go(D_ / 128, B_ * T_ / 128);
  gemm_bt<true><<<go, 256, 0, stream>>>(att_b, wo_b, d_out, B_ * T_, D_, D_);
}